// Round 3
// baseline (641.101 us; speedup 1.0000x reference)
//
#include <hip/hip_runtime.h>
#include <hip/hip_bf16.h>
#include <math.h>

#define NB 16          // batch
#define NC 256         // channels
#define NPTS 1000      // P*K points per batch
#define NN2 2000       // P*K*2
#define D1 1024        // FC1 hidden
#define KFLAT 16384    // C*64

typedef unsigned short ushort8 __attribute__((ext_vector_type(8)));

static __device__ __forceinline__ float bf2f(unsigned short v) {
    union { unsigned int u; float f; } x;
    x.u = ((unsigned int)v) << 16;
    return x.f;
}

// ---------------- kernel 0: transpose small weight matrices once
// R1 [128][258] -> R1t [258][128]; R2 [64][128] -> R2t [128][64];
// V1 [128][100] -> V1t [100][128]
__global__ __launch_bounds__(256) void k_prep(const float* __restrict__ R1,
                                              const float* __restrict__ R2,
                                              const float* __restrict__ V1,
                                              float* __restrict__ R1t,
                                              float* __restrict__ R2t_g,
                                              float* __restrict__ V1t_g) {
    int idx = blockIdx.x * 256 + threadIdx.x;
    if (idx < 33024) {                       // 128*258
        int j = idx / 258, k = idx % 258;
        R1t[k * 128 + j] = R1[idx];
    } else if (idx < 33024 + 8192) {         // 64*128
        int t = idx - 33024;
        int j = t >> 7, k = t & 127;
        R2t_g[k * 64 + j] = R2[t];
    } else if (idx < 33024 + 8192 + 12800) { // 128*100
        int t = idx - 41216;
        int j = t / 100, k = t % 100;
        V1t_g[k * 128 + j] = V1[t];
    }
}

// ---------------- kernel 1: 4x4 avg pool p4 (16,256,32,32) -> flat_bf (16,16384) bf16
__global__ __launch_bounds__(256) void k_pool(const float* __restrict__ p4,
                                              __hip_bfloat16* __restrict__ flat_bf) {
    int o = blockIdx.x * 256 + threadIdx.x;     // [0, 16*16384)
    int bc = o >> 6;                            // b*256 + c
    int ij = o & 63;
    int i = ij >> 3, j = ij & 7;
    const float* src = p4 + ((size_t)bc * 32 + i * 4) * 32 + j * 4;
    float s = 0.f;
#pragma unroll
    for (int di = 0; di < 4; ++di) {
        float4 v = *reinterpret_cast<const float4*>(src + di * 32);
        s += v.x + v.y + v.z + v.w;
    }
    flat_bf[o] = __float2bfloat16(s * (1.0f / 16.0f));
}

// ---------------- kernel 2: h = relu(flat @ W1^T + b1)  (16 x 1024)
// 512 threads = 8 waves: wave (half*4 + colw): column blk*4+colw, K-half `half`.
// flat staged in LDS as bf16 (halves LDS-pipe traffic); W1 2x float4/lane/iter
// with explicit cross-barrier prefetch.
__global__ __launch_bounds__(512) void k_fc1(const __hip_bfloat16* __restrict__ flat_bf,
                                             const float* __restrict__ W1,
                                             const float* __restrict__ b1,
                                             float* __restrict__ h) {
    __shared__ unsigned short tile[2 * 16 * 512];   // 32 KB, [half][m][512] bf16
    __shared__ float red[8 * 16];
    const int tid = threadIdx.x;
    const int wave = tid >> 6, lane = tid & 63;
    const int colw = wave & 3, half = wave >> 2;
    const int n = blockIdx.x * 4 + colw;            // [0,1024)
    float acc[16];
#pragma unroll
    for (int m = 0; m < 16; ++m) acc[m] = 0.f;
    const float4* W1r4 = reinterpret_cast<const float4*>(W1 + (size_t)n * KFLAT + half * 8192);
    const ushort8* flat8 = reinterpret_cast<const ushort8*>(flat_bf);
    ushort8* tile8 = reinterpret_cast<ushort8*>(tile);

    float4 wa = W1r4[lane * 2], wb = W1r4[lane * 2 + 1];
    for (int it = 0; it < 16; ++it) {
        __syncthreads();                             // prev compute done with LDS
#pragma unroll
        for (int r = 0; r < 4; ++r) {
            int idx = tid + r * 512;                 // [0,2048) ushort8 chunks
            int hh = idx >> 10, m = (idx >> 6) & 15, off = idx & 63;
            tile8[idx] = flat8[m * 2048 + hh * 1024 + it * 64 + off];
        }
        __syncthreads();
        float4 na = wa, nb = wb;
        if (it < 15) {
            na = W1r4[(it + 1) * 128 + lane * 2];
            nb = W1r4[(it + 1) * 128 + lane * 2 + 1];
        }
#pragma unroll
        for (int m = 0; m < 16; ++m) {
            ushort8 u = tile8[half * 1024 + m * 64 + lane];
            float s = wa.x * bf2f(u.s0) + wa.y * bf2f(u.s1)
                    + wa.z * bf2f(u.s2) + wa.w * bf2f(u.s3)
                    + wb.x * bf2f(u.s4) + wb.y * bf2f(u.s5)
                    + wb.z * bf2f(u.s6) + wb.w * bf2f(u.s7);
            acc[m] += s;
        }
        wa = na; wb = nb;
    }
#pragma unroll
    for (int m = 0; m < 16; ++m) {
        float v = acc[m];
#pragma unroll
        for (int off = 32; off > 0; off >>= 1) v += __shfl_xor(v, off, 64);
        acc[m] = v;
    }
    __syncthreads();
    if (lane == 0) {
#pragma unroll
        for (int m = 0; m < 16; ++m) red[wave * 16 + m] = acc[m];
    }
    __syncthreads();
    if (tid < 64) {
        int c = tid >> 4, m = tid & 15;
        float v = red[c * 16 + m] + red[(c + 4) * 16 + m] + b1[blockIdx.x * 4 + c];
        h[m * D1 + blockIdx.x * 4 + c] = fmaxf(v, 0.f);
    }
}

// ---------------- kernel 3: init = sigmoid(h @ W2^T + b2)  (16 x 2000)
__global__ __launch_bounds__(256) void k_fc2(const float* __restrict__ h,
                                             const float* __restrict__ W2,
                                             const float* __restrict__ b2,
                                             float* __restrict__ init_ws,
                                             float* __restrict__ out_init) {
    const int tid = threadIdx.x;
    const int wave = tid >> 6, lane = tid & 63;
    const int n = blockIdx.x * 4 + wave;        // [0,2000)
    float acc[16];
#pragma unroll
    for (int m = 0; m < 16; ++m) acc[m] = 0.f;
    const float4* W2r = reinterpret_cast<const float4*>(W2 + (size_t)n * D1);
    const float4* h4  = reinterpret_cast<const float4*>(h);
#pragma unroll
    for (int it = 0; it < 4; ++it) {
        int k4 = it * 64 + lane;                // float4 idx in row (256/row)
        float4 w = W2r[k4];
#pragma unroll
        for (int m = 0; m < 16; ++m) {
            float4 f = h4[m * 256 + k4];
            acc[m] += w.x * f.x + w.y * f.y + w.z * f.z + w.w * f.w;
        }
    }
    float bias = b2[n];
#pragma unroll
    for (int m = 0; m < 16; ++m) {
        float v = acc[m];
#pragma unroll
        for (int off = 32; off > 0; off >>= 1) v += __shfl_xor(v, off, 64);
        if (lane == 0) {
            float s = 1.f / (1.f + expf(-(v + bias)));
            init_ws[m * NN2 + n] = s;
            out_init[m * NN2 + n] = s;
        }
    }
}

// ---------------- kernel 4: bilinear sample, one block per (b,c) image
// Whole 64KB image staged into LDS with coalesced float4 loads; 1024 threads
// (16 waves) maximize outstanding loads during the HBM-bound phase.
// sampled layout: bf16 [b][c][n]
__global__ __launch_bounds__(1024) void k_sample(const float* __restrict__ p2,
                                                 const float* __restrict__ init_ws,
                                                 __hip_bfloat16* __restrict__ sampled) {
    __shared__ float img[128 * 128];            // 64 KB -> 2 blocks/CU
    const int bc = blockIdx.x;                  // b*256 + c
    const int b = bc >> 8;
    const float4* src4 = reinterpret_cast<const float4*>(p2 + (size_t)bc * 16384);
    float4* dst4 = reinterpret_cast<float4*>(img);
#pragma unroll
    for (int i = 0; i < 4; ++i)
        dst4[threadIdx.x + i * 1024] = src4[threadIdx.x + i * 1024];
    __syncthreads();
    const float* ip = init_ws + b * NN2;
    const int n = threadIdx.x;
    if (n < NPTS) {
        float2 sxy = *reinterpret_cast<const float2*>(ip + 2 * n);
        float x = sxy.x * 128.f - 0.5f;
        float y = sxy.y * 128.f - 0.5f;
        float x0f = floorf(x), y0f = floorf(y);
        float wx = x - x0f, wy = y - y0f;
        int x0 = (int)x0f, y0 = (int)y0f;
        int x1 = x0 + 1, y1 = y0 + 1;
        bool vx0 = (x0 >= 0) && (x0 <= 127);
        bool vx1 = (x1 >= 0) && (x1 <= 127);
        bool vy0 = (y0 >= 0) && (y0 <= 127);
        bool vy1 = (y1 >= 0) && (y1 <= 127);
        int cx0 = min(max(x0, 0), 127), cx1 = min(max(x1, 0), 127);
        int cy0 = min(max(y0, 0), 127), cy1 = min(max(y1, 0), 127);
        float v00 = (vx0 && vy0) ? img[cy0 * 128 + cx0] : 0.f;
        float v10 = (vx1 && vy0) ? img[cy0 * 128 + cx1] : 0.f;
        float v01 = (vx0 && vy1) ? img[cy1 * 128 + cx0] : 0.f;
        float v11 = (vx1 && vy1) ? img[cy1 * 128 + cx1] : 0.f;
        float r = v00 * (1.f - wx) * (1.f - wy) + v10 * wx * (1.f - wy)
                + v01 * (1.f - wx) * wy + v11 * wx * wy;
        sampled[(size_t)bc * NPTS + n] = __float2bfloat16(r);
    }
}

// ---------------- kernel 5: h1t = relu(feat @ R1^T + rb1), TRANSPOSED out
// per-batch GEMM M=128(j) N=1000(n) K=256. h1t layout [b][j][n] so k_r23
// can read point-rows coalesced (lane = point).
__global__ __launch_bounds__(256) void k_r1(const __hip_bfloat16* __restrict__ sampled,
                                            const float* __restrict__ init_ws,
                                            const float* __restrict__ R1t,
                                            const float* __restrict__ rb1,
                                            float* __restrict__ h1t) {
    __shared__ float As[64][128];   // [kk][j]
    __shared__ float Bs[64][32];    // [kk][n]
    const int tid = threadIdx.x;
    const int b = blockIdx.x >> 5;          // 32 n-tiles per batch
    const int n0 = (blockIdx.x & 31) * 32;
    const int nt = tid & 15;                // n-pair id (n fastest for store coalescing)
    const int jt = tid >> 4;                // [0,16): j quad id (8 j per thread)
    float acc[8][2];
#pragma unroll
    for (int a = 0; a < 8; ++a) { acc[a][0] = 0.f; acc[a][1] = 0.f; }

    for (int k0 = 0; k0 < 256; k0 += 64) {
        __syncthreads();
        for (int idx = tid; idx < 128 * 64; idx += 256) {
            int kk = idx >> 7, r = idx & 127;       // coalesced read, CF write
            As[kk][r] = R1t[(k0 + kk) * 128 + r];
        }
        for (int idx = tid; idx < 64 * 32; idx += 256) {
            int r = idx >> 5, col = idx & 31;
            int n = n0 + col;
            Bs[r][col] = (n < NPTS)
                ? __bfloat162float(sampled[((size_t)(b * 256 + k0 + r)) * NPTS + n])
                : 0.f;
        }
        __syncthreads();
#pragma unroll 8
        for (int kk = 0; kk < 64; ++kk) {
            float4 a0 = *reinterpret_cast<const float4*>(&As[kk][jt * 4]);
            float4 a1 = *reinterpret_cast<const float4*>(&As[kk][64 + jt * 4]);
            float2 bb = *reinterpret_cast<const float2*>(&Bs[kk][nt * 2]);
            float av[8] = {a0.x, a0.y, a0.z, a0.w, a1.x, a1.y, a1.z, a1.w};
#pragma unroll
            for (int a = 0; a < 8; ++a) {
                acc[a][0] += av[a] * bb.x;
                acc[a][1] += av[a] * bb.y;
            }
        }
    }
    // coord columns (K=256,257) + bias + relu + transposed store
    const int npair = n0 + nt * 2;
    float4 c4 = make_float4(0.f, 0.f, 0.f, 0.f);
    if (npair < NPTS)
        c4 = *reinterpret_cast<const float4*>(init_ws + b * NN2 + 2 * npair);
#pragma unroll
    for (int a = 0; a < 8; ++a) {
        int j = (a < 4) ? (jt * 4 + a) : (64 + jt * 4 + (a - 4));
        float rx = R1t[256 * 128 + j];
        float ry = R1t[257 * 128 + j];
        float bj = rb1[j];
        float v0 = fmaxf(acc[a][0] + rx * c4.x + ry * c4.y + bj, 0.f);
        float v1 = fmaxf(acc[a][1] + rx * c4.z + ry * c4.w + bj, 0.f);
        if (npair < NPTS) {
            float2 st = make_float2(v0, v1);
            *reinterpret_cast<float2*>(h1t + ((size_t)(b * 128 + j)) * NPTS + npair) = st;
        }
    }
}

// ---------------- kernel 6: h2 = relu(h1@R2^T+rb2); disp = tanh(h2@R3^T+rb3);
// refined = clip(init + 0.1*disp).
// lane = point. h1 row in 128 VGPRs (coalesced from h1t). R2t rows via
// thread-uniform addresses -> scalar loads. No LDS, no barriers, no shuffles.
__global__ __launch_bounds__(64) void k_r23(const float* __restrict__ h1t,
                                            const float* __restrict__ init_ws,
                                            const float* __restrict__ R2t_g,
                                            const float* __restrict__ rb2,
                                            const float* __restrict__ R3,
                                            const float* __restrict__ rb3,
                                            float* __restrict__ refined) {
    const int lane = threadIdx.x;
    const int wid = blockIdx.x;                 // [0,256)
    const int b = wid >> 4;
    const int n = (wid & 15) * 64 + lane;       // may exceed 999 in last tile
    const bool act = (n < NPTS);
    const int nc = act ? n : (NPTS - 1);

    // preload h1 row: 128 independent coalesced loads
    float hreg[128];
    const float* hp = h1t + (size_t)b * (128 * NPTS) + nc;
#pragma unroll
    for (int k = 0; k < 128; ++k) hreg[k] = hp[(size_t)k * NPTS];

    float acc[64];
#pragma unroll
    for (int j = 0; j < 64; ++j) acc[j] = rb2[j];

#pragma unroll
    for (int k = 0; k < 128; ++k) {
        const float* wr = R2t_g + k * 64;       // uniform -> s_load
#pragma unroll
        for (int j = 0; j < 64; ++j)
            acc[j] = fmaf(wr[j], hreg[k], acc[j]);
    }

    float d0 = 0.f, d1 = 0.f;
#pragma unroll
    for (int j = 0; j < 64; ++j) {
        float a = fmaxf(acc[j], 0.f);
        d0 = fmaf(R3[j], a, d0);
        d1 = fmaf(R3[64 + j], a, d1);
    }
    float2 ip = *reinterpret_cast<const float2*>(init_ws + b * NN2 + 2 * nc);
    float rx = ip.x + 0.1f * tanhf(d0 + rb3[0]);
    float ry = ip.y + 0.1f * tanhf(d1 + rb3[1]);
    rx = fminf(fmaxf(rx, 0.f), 1.f);
    ry = fminf(fmaxf(ry, 0.f), 1.f);
    if (act) {
        float2 st = make_float2(rx, ry);
        *reinterpret_cast<float2*>(refined + ((size_t)b * NPTS + n) * 2) = st;
    }
}

// ---------------- kernel 7: v = sigmoid(relu(pf@V1^T+vb1)@V2^T+vb2), 320 rows
__global__ __launch_bounds__(256) void k_vhead(const float* __restrict__ refined,
                                               const float* __restrict__ V1t_g,
                                               const float* __restrict__ vb1,
                                               const float* __restrict__ V2,
                                               const float* __restrict__ vb2,
                                               float* __restrict__ vout) {
    __shared__ float V1t[100][128]; // [k][j]
    __shared__ float pf[4][100];
    const int tid = threadIdx.x, wave = tid >> 6, lane = tid & 63;
    for (int idx = tid; idx < 100 * 128; idx += 256)
        V1t[idx >> 7][idx & 127] = V1t_g[idx];  // coalesced
    __syncthreads();
    const int row = blockIdx.x * 4 + wave;      // [0,320)
    const float* src = refined + row * 100;
    if (lane < 50) {
        pf[wave][lane] = src[lane];
        pf[wave][lane + 50] = src[lane + 50];
    }
    __syncthreads();
    float a0 = vb1[lane], a1 = vb1[64 + lane];
#pragma unroll 10
    for (int k = 0; k < 100; ++k) {
        float p = pf[wave][k];
        a0 += V1t[k][lane] * p;
        a1 += V1t[k][64 + lane] * p;
    }
    float s = fmaxf(a0, 0.f) * V2[lane] + fmaxf(a1, 0.f) * V2[64 + lane];
#pragma unroll
    for (int off = 32; off > 0; off >>= 1) s += __shfl_xor(s, off, 64);
    if (lane == 0) vout[row] = 1.f / (1.f + expf(-(s + vb2[0])));
}

extern "C" void kernel_launch(void* const* d_in, const int* in_sizes, int n_in,
                              void* d_out, int out_size, void* d_ws, size_t ws_size,
                              hipStream_t stream) {
    const float* p4  = (const float*)d_in[0];
    const float* p2  = (const float*)d_in[1];
    // d_in[2] segmentation is unused by the reference
    const float* W1  = (const float*)d_in[3];
    const float* b1  = (const float*)d_in[4];
    const float* W2  = (const float*)d_in[5];
    const float* b2  = (const float*)d_in[6];
    const float* R1  = (const float*)d_in[7];
    const float* rb1 = (const float*)d_in[8];
    const float* R2  = (const float*)d_in[9];
    const float* rb2 = (const float*)d_in[10];
    const float* R3  = (const float*)d_in[11];
    const float* rb3 = (const float*)d_in[12];
    const float* V1  = (const float*)d_in[13];
    const float* vb1 = (const float*)d_in[14];
    const float* V2  = (const float*)d_in[15];
    const float* vb2 = (const float*)d_in[16];
    float* out = (float*)d_out;   // [refined 32000][v 320][init 32000]

    char* ws = (char*)d_ws;
    __hip_bfloat16* flat_bf = (__hip_bfloat16*)(ws + 0);       //   524,288 B
    float* h    = (float*)(ws + 524288);                       //    65,536 B
    float* ipts = (float*)(ws + 589824);                       //   128,000 B
    float* h1t  = (float*)(ws + 717824);                       // 8,192,000 B
    __hip_bfloat16* samp = (__hip_bfloat16*)(ws + 8909824);    // 8,192,000 B
    float* R1t  = (float*)(ws + 17101824);                     //   132,096 B
    float* R2t_g= (float*)(ws + 17233920);                     //    32,768 B
    float* V1t_g= (float*)(ws + 17266688);                     //    51,200 B

    k_prep<<<212, 256, 0, stream>>>(R1, R2, V1, R1t, R2t_g, V1t_g);
    k_pool<<<1024, 256, 0, stream>>>(p4, flat_bf);
    k_fc1<<<256, 512, 0, stream>>>(flat_bf, W1, b1, h);
    k_fc2<<<500, 256, 0, stream>>>(h, W2, b2, ipts, out + 32320);
    k_sample<<<4096, 1024, 0, stream>>>(p2, ipts, samp);
    k_r1<<<512, 256, 0, stream>>>(samp, ipts, R1t, rb1, h1t);
    k_r23<<<256, 64, 0, stream>>>(h1t, ipts, R2t_g, rb2, R3, rb3, out);
    k_vhead<<<80, 256, 0, stream>>>(out, V1t_g, vb1, V2, vb2, out + 32000);
}

// Round 4
// 526.881 us; speedup vs baseline: 1.2168x; 1.2168x over previous
//
#include <hip/hip_runtime.h>
#include <hip/hip_bf16.h>
#include <math.h>

#define NB 16          // batch
#define NC 256         // channels
#define NPTS 1000      // P*K points per batch
#define NN2 2000       // P*K*2
#define D1 1024        // FC1 hidden
#define KFLAT 16384    // C*64

typedef unsigned short ushort8 __attribute__((ext_vector_type(8)));

static __device__ __forceinline__ float bf2f(unsigned short v) {
    union { unsigned int u; float f; } x;
    x.u = ((unsigned int)v) << 16;
    return x.f;
}

// ---------------- kernel 0: transpose small weight matrices once
// R1 [128][258] -> R1t [258][128]; V1 [128][100] -> V1t [100][128]
__global__ __launch_bounds__(256) void k_prep(const float* __restrict__ R1,
                                              const float* __restrict__ V1,
                                              float* __restrict__ R1t,
                                              float* __restrict__ V1t_g) {
    int idx = blockIdx.x * 256 + threadIdx.x;
    if (idx < 33024) {                       // 128*258
        int j = idx / 258, k = idx % 258;
        R1t[k * 128 + j] = R1[idx];
    } else if (idx < 33024 + 12800) {        // 128*100
        int t = idx - 33024;
        int j = t / 100, k = t % 100;
        V1t_g[k * 128 + j] = V1[t];
    }
}

// ---------------- kernel 1: 4x4 avg pool p4 (16,256,32,32) -> flat_bf (16,16384) bf16
__global__ __launch_bounds__(256) void k_pool(const float* __restrict__ p4,
                                              __hip_bfloat16* __restrict__ flat_bf) {
    int o = blockIdx.x * 256 + threadIdx.x;     // [0, 16*16384)
    int bc = o >> 6;                            // b*256 + c
    int ij = o & 63;
    int i = ij >> 3, j = ij & 7;
    const float* src = p4 + ((size_t)bc * 32 + i * 4) * 32 + j * 4;
    float s = 0.f;
#pragma unroll
    for (int di = 0; di < 4; ++di) {
        float4 v = *reinterpret_cast<const float4*>(src + di * 32);
        s += v.x + v.y + v.z + v.w;
    }
    flat_bf[o] = __float2bfloat16(s * (1.0f / 16.0f));
}

// ---------------- kernel 2: h = relu(flat @ W1^T + b1)  (16 x 1024)
// 512 threads = 8 waves: wave (half*4 + colw): column blk*4+colw, K-half `half`.
// flat staged in LDS as bf16; W1 2x float4/lane/iter with cross-barrier prefetch.
__global__ __launch_bounds__(512) void k_fc1(const __hip_bfloat16* __restrict__ flat_bf,
                                             const float* __restrict__ W1,
                                             const float* __restrict__ b1,
                                             float* __restrict__ h) {
    __shared__ unsigned short tile[2 * 16 * 512];   // 32 KB, [half][m][512] bf16
    __shared__ float red[8 * 16];
    const int tid = threadIdx.x;
    const int wave = tid >> 6, lane = tid & 63;
    const int colw = wave & 3, half = wave >> 2;
    const int n = blockIdx.x * 4 + colw;            // [0,1024)
    float acc[16];
#pragma unroll
    for (int m = 0; m < 16; ++m) acc[m] = 0.f;
    const float4* W1r4 = reinterpret_cast<const float4*>(W1 + (size_t)n * KFLAT + half * 8192);
    const ushort8* flat8 = reinterpret_cast<const ushort8*>(flat_bf);
    ushort8* tile8 = reinterpret_cast<ushort8*>(tile);

    float4 wa = W1r4[lane * 2], wb = W1r4[lane * 2 + 1];
    for (int it = 0; it < 16; ++it) {
        __syncthreads();                             // prev compute done with LDS
#pragma unroll
        for (int r = 0; r < 4; ++r) {
            int idx = tid + r * 512;                 // [0,2048) ushort8 chunks
            int hh = idx >> 10, m = (idx >> 6) & 15, off = idx & 63;
            tile8[idx] = flat8[m * 2048 + hh * 1024 + it * 64 + off];
        }
        __syncthreads();
        float4 na = wa, nb = wb;
        if (it < 15) {
            na = W1r4[(it + 1) * 128 + lane * 2];
            nb = W1r4[(it + 1) * 128 + lane * 2 + 1];
        }
#pragma unroll
        for (int m = 0; m < 16; ++m) {
            ushort8 u = tile8[half * 1024 + m * 64 + lane];
            float s = wa.x * bf2f(u.s0) + wa.y * bf2f(u.s1)
                    + wa.z * bf2f(u.s2) + wa.w * bf2f(u.s3)
                    + wb.x * bf2f(u.s4) + wb.y * bf2f(u.s5)
                    + wb.z * bf2f(u.s6) + wb.w * bf2f(u.s7);
            acc[m] += s;
        }
        wa = na; wb = nb;
    }
#pragma unroll
    for (int m = 0; m < 16; ++m) {
        float v = acc[m];
#pragma unroll
        for (int off = 32; off > 0; off >>= 1) v += __shfl_xor(v, off, 64);
        acc[m] = v;
    }
    __syncthreads();
    if (lane == 0) {
#pragma unroll
        for (int m = 0; m < 16; ++m) red[wave * 16 + m] = acc[m];
    }
    __syncthreads();
    if (tid < 64) {
        int c = tid >> 4, m = tid & 15;
        float v = red[c * 16 + m] + red[(c + 4) * 16 + m] + b1[blockIdx.x * 4 + c];
        h[m * D1 + blockIdx.x * 4 + c] = fmaxf(v, 0.f);
    }
}

// ---------------- kernel 3: init = sigmoid(h @ W2^T + b2)  (16 x 2000)
__global__ __launch_bounds__(256) void k_fc2(const float* __restrict__ h,
                                             const float* __restrict__ W2,
                                             const float* __restrict__ b2,
                                             float* __restrict__ init_ws,
                                             float* __restrict__ out_init) {
    const int tid = threadIdx.x;
    const int wave = tid >> 6, lane = tid & 63;
    const int n = blockIdx.x * 4 + wave;        // [0,2000)
    float acc[16];
#pragma unroll
    for (int m = 0; m < 16; ++m) acc[m] = 0.f;
    const float4* W2r = reinterpret_cast<const float4*>(W2 + (size_t)n * D1);
    const float4* h4  = reinterpret_cast<const float4*>(h);
#pragma unroll
    for (int it = 0; it < 4; ++it) {
        int k4 = it * 64 + lane;                // float4 idx in row (256/row)
        float4 w = W2r[k4];
#pragma unroll
        for (int m = 0; m < 16; ++m) {
            float4 f = h4[m * 256 + k4];
            acc[m] += w.x * f.x + w.y * f.y + w.z * f.z + w.w * f.w;
        }
    }
    float bias = b2[n];
#pragma unroll
    for (int m = 0; m < 16; ++m) {
        float v = acc[m];
#pragma unroll
        for (int off = 32; off > 0; off >>= 1) v += __shfl_xor(v, off, 64);
        if (lane == 0) {
            float s = 1.f / (1.f + expf(-(v + bias)));
            init_ws[m * NN2 + n] = s;
            out_init[m * NN2 + n] = s;
        }
    }
}

// ---------------- kernel 4: bilinear sample, one block per (b,c) image
// Whole 64KB image staged into LDS with coalesced float4 loads.
// sampled layout: bf16 [b][c][n]
__global__ __launch_bounds__(1024) void k_sample(const float* __restrict__ p2,
                                                 const float* __restrict__ init_ws,
                                                 __hip_bfloat16* __restrict__ sampled) {
    __shared__ float img[128 * 128];            // 64 KB -> 2 blocks/CU
    const int bc = blockIdx.x;                  // b*256 + c
    const int b = bc >> 8;
    const float4* src4 = reinterpret_cast<const float4*>(p2 + (size_t)bc * 16384);
    float4* dst4 = reinterpret_cast<float4*>(img);
#pragma unroll
    for (int i = 0; i < 4; ++i)
        dst4[threadIdx.x + i * 1024] = src4[threadIdx.x + i * 1024];
    __syncthreads();
    const float* ip = init_ws + b * NN2;
    const int n = threadIdx.x;
    if (n < NPTS) {
        float2 sxy = *reinterpret_cast<const float2*>(ip + 2 * n);
        float x = sxy.x * 128.f - 0.5f;
        float y = sxy.y * 128.f - 0.5f;
        float x0f = floorf(x), y0f = floorf(y);
        float wx = x - x0f, wy = y - y0f;
        int x0 = (int)x0f, y0 = (int)y0f;
        int x1 = x0 + 1, y1 = y0 + 1;
        bool vx0 = (x0 >= 0) && (x0 <= 127);
        bool vx1 = (x1 >= 0) && (x1 <= 127);
        bool vy0 = (y0 >= 0) && (y0 <= 127);
        bool vy1 = (y1 >= 0) && (y1 <= 127);
        int cx0 = min(max(x0, 0), 127), cx1 = min(max(x1, 0), 127);
        int cy0 = min(max(y0, 0), 127), cy1 = min(max(y1, 0), 127);
        float v00 = (vx0 && vy0) ? img[cy0 * 128 + cx0] : 0.f;
        float v10 = (vx1 && vy0) ? img[cy0 * 128 + cx1] : 0.f;
        float v01 = (vx0 && vy1) ? img[cy1 * 128 + cx0] : 0.f;
        float v11 = (vx1 && vy1) ? img[cy1 * 128 + cx1] : 0.f;
        float r = v00 * (1.f - wx) * (1.f - wy) + v10 * wx * (1.f - wy)
                + v01 * (1.f - wx) * wy + v11 * wx * wy;
        sampled[(size_t)bc * NPTS + n] = __float2bfloat16(r);
    }
}

// ---------------- kernel 5: h1t = relu(feat @ R1^T + rb1), TRANSPOSED out
// per-batch GEMM M=128(j) N=1000(n) K=256. h1t layout [b][j][n].
__global__ __launch_bounds__(256) void k_r1(const __hip_bfloat16* __restrict__ sampled,
                                            const float* __restrict__ init_ws,
                                            const float* __restrict__ R1t,
                                            const float* __restrict__ rb1,
                                            float* __restrict__ h1t) {
    __shared__ float As[64][128];   // [kk][j]
    __shared__ float Bs[64][32];    // [kk][n]
    const int tid = threadIdx.x;
    const int b = blockIdx.x >> 5;          // 32 n-tiles per batch
    const int n0 = (blockIdx.x & 31) * 32;
    const int nt = tid & 15;                // n-pair id (n fastest for store coalescing)
    const int jt = tid >> 4;                // [0,16): j quad id (8 j per thread)
    float acc[8][2];
#pragma unroll
    for (int a = 0; a < 8; ++a) { acc[a][0] = 0.f; acc[a][1] = 0.f; }

    for (int k0 = 0; k0 < 256; k0 += 64) {
        __syncthreads();
        for (int idx = tid; idx < 128 * 64; idx += 256) {
            int kk = idx >> 7, r = idx & 127;       // coalesced read, CF write
            As[kk][r] = R1t[(k0 + kk) * 128 + r];
        }
        for (int idx = tid; idx < 64 * 32; idx += 256) {
            int r = idx >> 5, col = idx & 31;
            int n = n0 + col;
            Bs[r][col] = (n < NPTS)
                ? __bfloat162float(sampled[((size_t)(b * 256 + k0 + r)) * NPTS + n])
                : 0.f;
        }
        __syncthreads();
#pragma unroll 8
        for (int kk = 0; kk < 64; ++kk) {
            float4 a0 = *reinterpret_cast<const float4*>(&As[kk][jt * 4]);
            float4 a1 = *reinterpret_cast<const float4*>(&As[kk][64 + jt * 4]);
            float2 bb = *reinterpret_cast<const float2*>(&Bs[kk][nt * 2]);
            float av[8] = {a0.x, a0.y, a0.z, a0.w, a1.x, a1.y, a1.z, a1.w};
#pragma unroll
            for (int a = 0; a < 8; ++a) {
                acc[a][0] += av[a] * bb.x;
                acc[a][1] += av[a] * bb.y;
            }
        }
    }
    // coord columns (K=256,257) + bias + relu + transposed store
    const int npair = n0 + nt * 2;
    float4 c4 = make_float4(0.f, 0.f, 0.f, 0.f);
    if (npair < NPTS)
        c4 = *reinterpret_cast<const float4*>(init_ws + b * NN2 + 2 * npair);
#pragma unroll
    for (int a = 0; a < 8; ++a) {
        int j = (a < 4) ? (jt * 4 + a) : (64 + jt * 4 + (a - 4));
        float rx = R1t[256 * 128 + j];
        float ry = R1t[257 * 128 + j];
        float bj = rb1[j];
        float v0 = fmaxf(acc[a][0] + rx * c4.x + ry * c4.y + bj, 0.f);
        float v1 = fmaxf(acc[a][1] + rx * c4.z + ry * c4.w + bj, 0.f);
        if (npair < NPTS) {
            float2 st = make_float2(v0, v1);
            *reinterpret_cast<float2*>(h1t + ((size_t)(b * 128 + j)) * NPTS + npair) = st;
        }
    }
}

// ---------------- kernel 6: h2 = relu(h1@R2^T+rb2); disp = tanh(h2@R3^T+rb3);
// refined = clip(init + 0.1*disp).
// Block = 512 threads (8 waves) per 64-point tile -> 2048 waves total.
// h1t tile (128x64 = 32KB) staged in LDS; lane = point; each wave owns an
// 8-wide j-slice with wave-uniform (readfirstlane) weight addresses -> s_load.
__global__ __launch_bounds__(512) void k_r23(const float* __restrict__ h1t,
                                             const float* __restrict__ init_ws,
                                             const float* __restrict__ R2,
                                             const float* __restrict__ rb2,
                                             const float* __restrict__ R3,
                                             const float* __restrict__ rb3,
                                             float* __restrict__ refined) {
    __shared__ float hbuf[128][64];   // 32 KB, [k][n] -- 2-way bank alias = free
    __shared__ float part[8][2][64];  // per-wave partial d0/d1
    const int tid = threadIdx.x;
    const int wave = tid >> 6, lane = tid & 63;
    const int b = blockIdx.x >> 4;
    const int n0 = (blockIdx.x & 15) * 64;
    const int nc = min(n0 + lane, NPTS - 1);

    // stage h1t tile: each wave loads 16 rows, coalesced 256B per row
    const float* hsrc = h1t + (size_t)b * (128 * NPTS) + nc;
#pragma unroll
    for (int i = 0; i < 16; ++i) {
        int r = wave * 16 + i;
        hbuf[r][lane] = hsrc[(size_t)r * NPTS];
    }
    __syncthreads();

    const int jb = __builtin_amdgcn_readfirstlane(wave * 8);  // wave-uniform j base
    float acc[8];
#pragma unroll
    for (int jj = 0; jj < 8; ++jj) acc[jj] = rb2[jb + jj];
#pragma unroll 4
    for (int k = 0; k < 128; ++k) {
        float hv = hbuf[k][lane];
#pragma unroll
        for (int jj = 0; jj < 8; ++jj)
            acc[jj] = fmaf(R2[(jb + jj) * 128 + k], hv, acc[jj]);
    }
    float d0 = 0.f, d1 = 0.f;
#pragma unroll
    for (int jj = 0; jj < 8; ++jj) {
        float a = fmaxf(acc[jj], 0.f);
        d0 = fmaf(R3[jb + jj], a, d0);
        d1 = fmaf(R3[64 + jb + jj], a, d1);
    }
    part[wave][0][lane] = d0;
    part[wave][1][lane] = d1;
    __syncthreads();
    if (tid < 64) {
        float s0 = 0.f, s1 = 0.f;
#pragma unroll
        for (int w = 0; w < 8; ++w) { s0 += part[w][0][tid]; s1 += part[w][1][tid]; }
        float2 ip = *reinterpret_cast<const float2*>(init_ws + b * NN2 + 2 * nc);
        float rx = fminf(fmaxf(ip.x + 0.1f * tanhf(s0 + rb3[0]), 0.f), 1.f);
        float ry = fminf(fmaxf(ip.y + 0.1f * tanhf(s1 + rb3[1]), 0.f), 1.f);
        if (n0 + tid < NPTS) {
            *reinterpret_cast<float2*>(refined + ((size_t)b * NPTS + n0 + tid) * 2)
                = make_float2(rx, ry);
        }
    }
}

// ---------------- kernel 7: v = sigmoid(relu(pf@V1^T+vb1)@V2^T+vb2), 320 rows
__global__ __launch_bounds__(256) void k_vhead(const float* __restrict__ refined,
                                               const float* __restrict__ V1t_g,
                                               const float* __restrict__ vb1,
                                               const float* __restrict__ V2,
                                               const float* __restrict__ vb2,
                                               float* __restrict__ vout) {
    __shared__ float V1t[100][128]; // [k][j]
    __shared__ float pf[4][100];
    const int tid = threadIdx.x, wave = tid >> 6, lane = tid & 63;
    for (int idx = tid; idx < 100 * 128; idx += 256)
        V1t[idx >> 7][idx & 127] = V1t_g[idx];  // coalesced
    __syncthreads();
    const int row = blockIdx.x * 4 + wave;      // [0,320)
    const float* src = refined + row * 100;
    if (lane < 50) {
        pf[wave][lane] = src[lane];
        pf[wave][lane + 50] = src[lane + 50];
    }
    __syncthreads();
    float a0 = vb1[lane], a1 = vb1[64 + lane];
#pragma unroll 10
    for (int k = 0; k < 100; ++k) {
        float p = pf[wave][k];
        a0 += V1t[k][lane] * p;
        a1 += V1t[k][64 + lane] * p;
    }
    float s = fmaxf(a0, 0.f) * V2[lane] + fmaxf(a1, 0.f) * V2[64 + lane];
#pragma unroll
    for (int off = 32; off > 0; off >>= 1) s += __shfl_xor(s, off, 64);
    if (lane == 0) vout[row] = 1.f / (1.f + expf(-(s + vb2[0])));
}

extern "C" void kernel_launch(void* const* d_in, const int* in_sizes, int n_in,
                              void* d_out, int out_size, void* d_ws, size_t ws_size,
                              hipStream_t stream) {
    const float* p4  = (const float*)d_in[0];
    const float* p2  = (const float*)d_in[1];
    // d_in[2] segmentation is unused by the reference
    const float* W1  = (const float*)d_in[3];
    const float* b1  = (const float*)d_in[4];
    const float* W2  = (const float*)d_in[5];
    const float* b2  = (const float*)d_in[6];
    const float* R1  = (const float*)d_in[7];
    const float* rb1 = (const float*)d_in[8];
    const float* R2  = (const float*)d_in[9];
    const float* rb2 = (const float*)d_in[10];
    const float* R3  = (const float*)d_in[11];
    const float* rb3 = (const float*)d_in[12];
    const float* V1  = (const float*)d_in[13];
    const float* vb1 = (const float*)d_in[14];
    const float* V2  = (const float*)d_in[15];
    const float* vb2 = (const float*)d_in[16];
    float* out = (float*)d_out;   // [refined 32000][v 320][init 32000]

    char* ws = (char*)d_ws;
    __hip_bfloat16* flat_bf = (__hip_bfloat16*)(ws + 0);       //   524,288 B
    float* h    = (float*)(ws + 524288);                       //    65,536 B
    float* ipts = (float*)(ws + 589824);                       //   128,000 B
    float* h1t  = (float*)(ws + 717824);                       // 8,192,000 B
    __hip_bfloat16* samp = (__hip_bfloat16*)(ws + 8909824);    // 8,192,000 B
    float* R1t  = (float*)(ws + 17101824);                     //   132,096 B
    float* V1t_g= (float*)(ws + 17233920);                     //    51,200 B

    k_prep<<<180, 256, 0, stream>>>(R1, V1, R1t, V1t_g);
    k_pool<<<1024, 256, 0, stream>>>(p4, flat_bf);
    k_fc1<<<256, 512, 0, stream>>>(flat_bf, W1, b1, h);
    k_fc2<<<500, 256, 0, stream>>>(h, W2, b2, ipts, out + 32320);
    k_sample<<<4096, 1024, 0, stream>>>(p2, ipts, samp);
    k_r1<<<512, 256, 0, stream>>>(samp, ipts, R1t, rb1, h1t);
    k_r23<<<256, 512, 0, stream>>>(h1t, ipts, R2, rb2, R3, rb3, out);
    k_vhead<<<80, 256, 0, stream>>>(out, V1t_g, vb1, V2, vb2, out + 32000);
}